// Round 6
// baseline (207.022 us; speedup 1.0000x reference)
//
#include <hip/hip_runtime.h>
#include <hip/hip_bf16.h>
#include <stdint.h>

typedef __attribute__((ext_vector_type(8))) short bf16x8;
typedef __attribute__((ext_vector_type(4))) float f32x4;

// LDS map (bytes):
//   [0, 90112)  weight B-fragments, bf16: frag f at byte f*1024 + lane*16
//     f 0..23: QKV (nt=sel*4+head, f=nt*2+ks)   f 24..55: W1 (f=24+nt*2+ks)
//     f 56..87: W2 (f=56+ksl*4+nt)              (Wp lives in VGPRs)
//   [90112, 163840) 12 per-wave arenas of 6144 B, heavily overlaid:
//     +0    qH [4][16][16] bf16   (P overlay; also hB[16][72] bounce: h/O/sa/h2/ff;
//                                  also sl0@+0, sl1@+1280 in MLP)
//     +2048 kH [4][16][16]
//     +4096 vT [4][16 d][16 tk]
//   Overlay safety: per-wave DS ops execute in order; stores of MFMA results
//   can't pass the fragment reads they depend on (wave-level lgkm waits);
//   cross-lane write->read crossings all have WSYNC.

static __device__ __forceinline__ unsigned short f2bf(float f) {
    union { __hip_bfloat16 h; unsigned short u; } cv;
    cv.h = __float2bfloat16(f);
    return cv.u;
}
static __device__ __forceinline__ unsigned int f2bf2(float a, float b) {
    return (unsigned int)f2bf(a) | ((unsigned int)f2bf(b) << 16);
}
static __device__ __forceinline__ float blo(unsigned int w) { return __uint_as_float(w << 16); }
static __device__ __forceinline__ float bhi(unsigned int w) { return __uint_as_float(w & 0xffff0000u); }

// Per-wave phase fence: drain LDS ops, forbid compiler motion across (rule #18).
#define WSYNC() do { asm volatile("s_waitcnt lgkmcnt(0)" ::: "memory"); \
                     __builtin_amdgcn_sched_barrier(0); } while (0)

__global__ __launch_bounds__(768, 3)
void fused_block(const float* __restrict__ xg,
                 const float* __restrict__ Wq, const float* __restrict__ Wk,
                 const float* __restrict__ Wv, const float* __restrict__ Wp,
                 const float* __restrict__ bp, const float* __restrict__ W1,
                 const float* __restrict__ b1, const float* __restrict__ W2,
                 const float* __restrict__ b2, const float* __restrict__ g1,
                 const float* __restrict__ be1, const float* __restrict__ g2,
                 const float* __restrict__ be2, float* __restrict__ out,
                 int nPairsTotal)
{
    __shared__ __align__(16) unsigned char LDS[163840];

    const int tid  = threadIdx.x;
    const int lane = tid & 63;
    const int wid  = tid >> 6;        // 0..11
    const int fr   = lane & 15;       // MFMA fragment row/col index
    const int fg   = lane >> 4;       // MFMA fragment k-group
    const int xr   = lane >> 2;       // x row owned by this lane (0..15)
    const int xc   = (lane & 3) * 16; // x col base

    // ---------------- weight preload into LDS (bf16 fragments) ----------------
    {
        unsigned short* lw = (unsigned short*)LDS;
        #pragma unroll 1
        for (int e = tid; e < 45056; e += 768) {
            int j  = e & 7;
            int ln = (e >> 3) & 63;
            float src;
            if (e < 12288) {                       // QKV: col = 16*(sel*4+h)+d
                int ks = (e >> 9) & 1, nt = e >> 10;
                int k = 8*(ln>>4) + j + 32*ks;
                int d = ln & 15, h = nt & 3, sel = nt >> 2;
                const float* W = (sel == 0) ? Wq : ((sel == 1) ? Wk : Wv);
                src = W[h*1024 + k*16 + d];
            } else if (e < 28672) {                // W1 [64 x 256]
                int t = e - 12288;
                int ks = (t >> 9) & 1, nt = t >> 10;
                int k = 8*(ln>>4) + j + 32*ks;
                src = W1[k*256 + 16*nt + (ln & 15)];
            } else {                               // W2 [256 x 64]
                int t = e - 28672;
                int nt = (t >> 9) & 3, ksl = t >> 11;
                int k = 32*ksl + 8*(ln>>4) + j;
                src = W2[k*64 + 16*nt + (ln & 15)];
            }
            lw[e] = f2bf(src);
        }
    }

    // Wp fragments in registers
    bf16x8 wpf[4][2];
    #pragma unroll
    for (int nt = 0; nt < 4; ++nt)
        #pragma unroll
        for (int ks = 0; ks < 2; ++ks) {
            bf16x8 v;
            #pragma unroll
            for (int j = 0; j < 8; ++j)
                v[j] = (short)f2bf(Wp[(8*fg + j + 32*ks)*64 + 16*nt + fr]);
            wpf[nt][ks] = v;
        }

    // per-lane parameters
    float g1v[16], be1v[16], g2v[16], be2v[16];
    #pragma unroll
    for (int j = 0; j < 16; ++j) {
        int c = xc + j;
        g1v[j] = g1[c]; be1v[j] = be1[c]; g2v[j] = g2[c]; be2v[j] = be2[c];
    }
    float b1v[16], bpv[4], b2v[4];
    #pragma unroll
    for (int nt = 0; nt < 16; ++nt) b1v[nt] = b1[16*nt + fr];
    #pragma unroll
    for (int nt = 0; nt < 4; ++nt) { bpv[nt] = bp[16*nt + fr]; b2v[nt] = b2[16*nt + fr]; }

    __syncthreads();

    unsigned char* arena = LDS + 90112 + wid * 6144;
    unsigned short* qH  = (unsigned short*)(arena);          // + P overlay
    unsigned short* kH  = (unsigned short*)(arena + 2048);
    unsigned short* vT  = (unsigned short*)(arena + 4096);
    unsigned short* hB  = (unsigned short*)(arena);          // [16][72] bounce overlay
    unsigned short* sl0 = (unsigned short*)(arena);          // MLP slice dbuf overlay
    unsigned short* sl1 = (unsigned short*)(arena + 1280);

    // B-fragment read from weight LDS
    #define WB(F) (*(const bf16x8*)(LDS + ((F) << 10) + (lane << 4)))

    const int pipe = blockIdx.x * 12 + wid;   // 256 blocks * 12 waves = 3072 pipes

    const bf16x8 zero8 = {0,0,0,0,0,0,0,0};
    const short onebf = (short)0x3F80;
    const bf16x8 ones8 = {onebf,onebf,onebf,onebf,onebf,onebf,onebf,onebf};

    // prefetch first tile
    f32x4 xn[4];
    if (pipe < nPairsTotal) {
        const float* xb0 = xg + (size_t)pipe * 1024;
        #pragma unroll
        for (int i = 0; i < 4; ++i)
            xn[i] = *(const f32x4*)(xb0 + xr*64 + xc + 4*i);
    }

    #pragma unroll 1
    for (int gp = pipe; gp < nPairsTotal; gp += 3072) {
        float* ob = out + (size_t)gp * 1024;

        f32x4 xv[4];
        #pragma unroll
        for (int i = 0; i < 4; ++i) xv[i] = xn[i];

        // issue next-tile prefetch (in flight across the whole iteration)
        {
            int gpn = gp + 3072;
            if (gpn < nPairsTotal) {
                const float* xbn = xg + (size_t)gpn * 1024;
                #pragma unroll
                for (int i = 0; i < 4; ++i)
                    xn[i] = *(const f32x4*)(xbn + xr*64 + xc + 4*i);
            }
        }

        // ---- LN1 -> h (bf16) -> hB ----
        {
            float s = 0.f, ss = 0.f;
            #pragma unroll
            for (int i = 0; i < 4; ++i)
                #pragma unroll
                for (int j = 0; j < 4; ++j) { float v = xv[i][j]; s += v; ss += v*v; }
            s += __shfl_xor(s, 1, 64); ss += __shfl_xor(ss, 1, 64);
            s += __shfl_xor(s, 2, 64); ss += __shfl_xor(ss, 2, 64);
            float mu  = s * 0.015625f;
            float inv = rsqrtf(ss * 0.015625f - mu*mu + 1e-5f);
            #pragma unroll
            for (int i = 0; i < 4; ++i) {
                float y0 = (xv[i][0]-mu)*inv*g1v[4*i+0] + be1v[4*i+0];
                float y1 = (xv[i][1]-mu)*inv*g1v[4*i+1] + be1v[4*i+1];
                float y2 = (xv[i][2]-mu)*inv*g1v[4*i+2] + be1v[4*i+2];
                float y3 = (xv[i][3]-mu)*inv*g1v[4*i+3] + be1v[4*i+3];
                *((uint2*)(hB + xr*72 + xc + 4*i)) = make_uint2(f2bf2(y0,y1), f2bf2(y2,y3));
            }
        }
        WSYNC();

        // ---- QKV = h @ [Wq|Wk|Wv] -> qH/kH/vT (overlays hB; a-reads gate writes) ----
        {
            bf16x8 a0 = *(const bf16x8*)(hB + fr*72 + 8*fg);
            bf16x8 a1 = *(const bf16x8*)(hB + fr*72 + 8*fg + 32);
            #pragma unroll
            for (int nt = 0; nt < 12; ++nt) {
                bf16x8 u0 = WB(nt*2+0);
                bf16x8 u1 = WB(nt*2+1);
                f32x4 acc = {0.f, 0.f, 0.f, 0.f};
                acc = __builtin_amdgcn_mfma_f32_16x16x32_bf16(a0, u0, acc, 0, 0, 0);
                acc = __builtin_amdgcn_mfma_f32_16x16x32_bf16(a1, u1, acc, 0, 0, 0);
                int hd = nt & 3;
                if (nt < 4) {
                    #pragma unroll
                    for (int r = 0; r < 4; ++r)
                        qH[hd*256 + (4*fg + r)*16 + fr] = f2bf(acc[r]);
                } else if (nt < 8) {
                    #pragma unroll
                    for (int r = 0; r < 4; ++r)
                        kH[hd*256 + (4*fg + r)*16 + fr] = f2bf(acc[r]);
                } else {   // transposed [d=fr][tk=4fg+r]; r consecutive -> packed store
                    *((uint2*)(vT + hd*256 + fr*16 + 4*fg)) =
                        make_uint2(f2bf2(acc[0],acc[1]), f2bf2(acc[2],acc[3]));
                }
            }
        }
        WSYNC();

        // ---- attention scores + exp (no max-sub; |s|<=~2 by construction) ----
        #pragma unroll
        for (int hd = 0; hd < 4; ++hd) {
            bf16x8 qf = zero8, kf = zero8;
            if (fg < 2) {
                qf = *(const bf16x8*)(qH + hd*256 + fr*16 + 8*fg);
                kf = *(const bf16x8*)(kH + hd*256 + fr*16 + 8*fg);
            }
            f32x4 s = {0.f,0.f,0.f,0.f};
            s = __builtin_amdgcn_mfma_f32_16x16x32_bf16(qf, kf, s, 0, 0, 0);
            #pragma unroll
            for (int r = 0; r < 4; ++r) {   // D: S[row=4fg+r][tk=fr]
                int row = 4*fg + r;
                bool valid = (((row ^ fr) & 8) == 0) && ((fr & 7) <= (row & 7));
                float e = valid ? __expf(s[r] * 0.125f) : 0.f;   // scale = C^-0.5
                qH[hd*256 + row*16 + fr] = f2bf(e);              // P overlays qH
            }
        }
        WSYNC();

        // ---- PV + ones-MFMA row-sum; O -> hB (clobbers P/kH: all reads first) ----
        {
            f32x4 o[4], rs[4];
            #pragma unroll
            for (int pp = 0; pp < 2; ++pp) {       // heads in pairs (reg pressure)
                bf16x8 pf0 = zero8, vf0 = zero8, pf1 = zero8, vf1 = zero8;
                if (fg < 2) {
                    pf0 = *(const bf16x8*)(qH + (2*pp+0)*256 + fr*16 + 8*fg);
                    vf0 = *(const bf16x8*)(vT + (2*pp+0)*256 + fr*16 + 8*fg);
                    pf1 = *(const bf16x8*)(qH + (2*pp+1)*256 + fr*16 + 8*fg);
                    vf1 = *(const bf16x8*)(vT + (2*pp+1)*256 + fr*16 + 8*fg);
                }
                f32x4 z = {0.f,0.f,0.f,0.f};
                o[2*pp+0]  = __builtin_amdgcn_mfma_f32_16x16x32_bf16(pf0, vf0,   z, 0,0,0);
                rs[2*pp+0] = __builtin_amdgcn_mfma_f32_16x16x32_bf16(pf0, ones8, z, 0,0,0);
                o[2*pp+1]  = __builtin_amdgcn_mfma_f32_16x16x32_bf16(pf1, vf1,   z, 0,0,0);
                rs[2*pp+1] = __builtin_amdgcn_mfma_f32_16x16x32_bf16(pf1, ones8, z, 0,0,0);
            }
            WSYNC();   // all P/vT reads drained before O stores below
            #pragma unroll
            for (int hd = 0; hd < 4; ++hd)
                #pragma unroll
                for (int r = 0; r < 4; ++r) {
                    float ov = o[hd][r] * __builtin_amdgcn_rcpf(rs[hd][r]);
                    hB[(4*fg + r)*72 + 16*hd + fr] = f2bf(ov);
                }
        }
        WSYNC();

        // ---- proj: sa = attn @ Wp + bp (reads hB, rewrites hB; MFMA-gated) ----
        {
            bf16x8 p0 = *(const bf16x8*)(hB + fr*72 + 8*fg);
            bf16x8 p1 = *(const bf16x8*)(hB + fr*72 + 8*fg + 32);
            f32x4 sacc[4];
            #pragma unroll
            for (int nt = 0; nt < 4; ++nt) {
                f32x4 acc = {0.f,0.f,0.f,0.f};
                acc = __builtin_amdgcn_mfma_f32_16x16x32_bf16(p0, wpf[nt][0], acc, 0,0,0);
                acc = __builtin_amdgcn_mfma_f32_16x16x32_bf16(p1, wpf[nt][1], acc, 0,0,0);
                sacc[nt] = acc;
            }
            #pragma unroll
            for (int nt = 0; nt < 4; ++nt)
                #pragma unroll
                for (int r = 0; r < 4; ++r)
                    hB[(4*fg + r)*72 + 16*nt + fr] = f2bf(sacc[nt][r] + bpv[nt]);
        }
        WSYNC();

        // ---- residual 1 (own cells), LN2 in-place -> hB ----
        #pragma unroll
        for (int i = 0; i < 4; ++i) {
            uint2 w = *((const uint2*)(hB + xr*72 + xc + 4*i));
            xv[i][0] += blo(w.x); xv[i][1] += bhi(w.x);
            xv[i][2] += blo(w.y); xv[i][3] += bhi(w.y);
        }
        {
            float s = 0.f, ss = 0.f;
            #pragma unroll
            for (int i = 0; i < 4; ++i)
                #pragma unroll
                for (int j = 0; j < 4; ++j) { float v = xv[i][j]; s += v; ss += v*v; }
            s += __shfl_xor(s, 1, 64); ss += __shfl_xor(ss, 1, 64);
            s += __shfl_xor(s, 2, 64); ss += __shfl_xor(ss, 2, 64);
            float mu  = s * 0.015625f;
            float inv = rsqrtf(ss * 0.015625f - mu*mu + 1e-5f);
            #pragma unroll
            for (int i = 0; i < 4; ++i) {
                float y0 = (xv[i][0]-mu)*inv*g2v[4*i+0] + be2v[4*i+0];
                float y1 = (xv[i][1]-mu)*inv*g2v[4*i+1] + be2v[4*i+1];
                float y2 = (xv[i][2]-mu)*inv*g2v[4*i+2] + be2v[4*i+2];
                float y3 = (xv[i][3]-mu)*inv*g2v[4*i+3] + be2v[4*i+3];
                *((uint2*)(hB + xr*72 + xc + 4*i)) = make_uint2(f2bf2(y0,y1), f2bf2(y2,y3));
            }
        }
        WSYNC();

        // ---- MLP, software-pipelined: W2(np-1) overlaps slice-store(np) ----
        bf16x8 c0 = *(const bf16x8*)(hB + fr*72 + 8*fg);
        bf16x8 c1 = *(const bf16x8*)(hB + fr*72 + 8*fg + 32);
        f32x4 ff[4];
        #pragma unroll
        for (int nt = 0; nt < 4; ++nt) { f32x4 z = {0.f,0.f,0.f,0.f}; ff[nt] = z; }

        #pragma unroll
        for (int q = 0; q < 2; ++q) {          // prologue: W1 tiles of np=0 -> sl0
            f32x4 acc = {0.f,0.f,0.f,0.f};
            acc = __builtin_amdgcn_mfma_f32_16x16x32_bf16(c0, WB(24 + q*2 + 0), acc, 0,0,0);
            acc = __builtin_amdgcn_mfma_f32_16x16x32_bf16(c1, WB(24 + q*2 + 1), acc, 0,0,0);
            #pragma unroll
            for (int r = 0; r < 4; ++r)
                sl0[(4*fg + r)*40 + 16*q + fr] = f2bf(fmaxf(acc[r] + b1v[q], 0.f));
        }
        WSYNC();
        bf16x8 asv = *(const bf16x8*)(sl0 + fr*40 + 8*fg);

        #pragma unroll
        for (int np = 1; np < 8; ++np) {
            unsigned short* sl = (np & 1) ? sl1 : sl0;
            #pragma unroll
            for (int q = 0; q < 2; ++q) {      // W1 tiles of np
                int nt1 = 2*np + q;
                f32x4 acc = {0.f,0.f,0.f,0.f};
                acc = __builtin_amdgcn_mfma_f32_16x16x32_bf16(c0, WB(24 + nt1*2 + 0), acc, 0,0,0);
                acc = __builtin_amdgcn_mfma_f32_16x16x32_bf16(c1, WB(24 + nt1*2 + 1), acc, 0,0,0);
                #pragma unroll
                for (int r = 0; r < 4; ++r)
                    sl[(4*fg + r)*40 + 16*q + fr] = f2bf(fmaxf(acc[r] + b1v[nt1], 0.f));
            }
            #pragma unroll
            for (int nt2 = 0; nt2 < 4; ++nt2)  // W2 of np-1 (overlaps store latency)
                ff[nt2] = __builtin_amdgcn_mfma_f32_16x16x32_bf16(
                              asv, WB(56 + (np-1)*4 + nt2), ff[nt2], 0,0,0);
            WSYNC();
            asv = *(const bf16x8*)(sl + fr*40 + 8*fg);
        }
        #pragma unroll
        for (int nt2 = 0; nt2 < 4; ++nt2)      // epilogue: W2 of np=7
            ff[nt2] = __builtin_amdgcn_mfma_f32_16x16x32_bf16(
                          asv, WB(56 + 28 + nt2), ff[nt2], 0,0,0);

        // ---- +b2 -> hB (clobbers slices; gated by last slice read via MFMA) ----
        #pragma unroll
        for (int nt2 = 0; nt2 < 4; ++nt2)
            #pragma unroll
            for (int r = 0; r < 4; ++r)
                hB[(4*fg + r)*72 + 16*nt2 + fr] = f2bf(ff[nt2][r] + b2v[nt2]);
        WSYNC();

        // ---- residual 2 + store ----
        #pragma unroll
        for (int i = 0; i < 4; ++i) {
            uint2 w = *((const uint2*)(hB + xr*72 + xc + 4*i));
            f32x4 o = xv[i];
            o[0] += blo(w.x); o[1] += bhi(w.x);
            o[2] += blo(w.y); o[3] += bhi(w.y);
            *((f32x4*)(ob + xr*64 + xc + 4*i)) = o;
        }
        WSYNC();   // hB reads drained before next iteration's LN1 writes
    }
    #undef WB
}

extern "C" void kernel_launch(void* const* d_in, const int* in_sizes, int n_in,
                              void* d_out, int out_size, void* d_ws, size_t ws_size,
                              hipStream_t stream) {
    const float* x   = (const float*)d_in[0];
    const float* Wq  = (const float*)d_in[1];
    const float* Wk  = (const float*)d_in[2];
    const float* Wv  = (const float*)d_in[3];
    const float* Wp  = (const float*)d_in[4];
    const float* bp  = (const float*)d_in[5];
    const float* W1  = (const float*)d_in[6];
    const float* b1  = (const float*)d_in[7];
    const float* W2  = (const float*)d_in[8];
    const float* b2  = (const float*)d_in[9];
    const float* g1  = (const float*)d_in[10];
    const float* be1 = (const float*)d_in[11];
    const float* g2  = (const float*)d_in[12];
    const float* be2 = (const float*)d_in[13];
    int nPairs = in_sizes[0] / 1024;   // (B*T*C) / (2*8*64) = 32768
    fused_block<<<dim3(256), dim3(768), 0, stream>>>(
        x, Wq, Wk, Wv, Wp, bp, W1, b1, W2, b2, g1, be1, g2, be2,
        (float*)d_out, nPairs);
}

// Round 7
// 202.039 us; speedup vs baseline: 1.0247x; 1.0247x over previous
//
#include <hip/hip_runtime.h>
#include <hip/hip_bf16.h>
#include <stdint.h>

typedef __attribute__((ext_vector_type(8))) short bf16x8;
typedef __attribute__((ext_vector_type(4))) float f32x4;

// LDS map (bytes):
//   [0, 90112)  weight B-fragments, bf16: frag f at byte f*1024 + lane*16
//     f 0..23: QKV (nt=sel*4+head, f=nt*2+ks)   f 24..55: W1 (f=24+nt*2+ks)
//     f 56..87: W2 (f=56+ksl*4+nt)              (Wp lives in VGPRs)
//   [90112, 163840) 12 per-wave arenas of 6144 B, heavily overlaid:
//     +0    qH [4][16][16] bf16  (P overlay; hB[16][72] bounce; sl0/sl1 in MLP)
//     +2048 kH [4][16][16]       (+ f32 x/out stage overlay, 4 KB @ +2048)
//     +4096 vT [4][16 d][16 tk]
//   Overlay safety: per-wave DS ops execute in order; all read->write
//   crossings are ordered by program order within the wave (+ WSYNC /
//   sched_barrier at phase boundaries). Global loads/stores are
//   per-instruction contiguous (1 KB/instr) to avoid partial-sector
//   HBM amplification (round-6 lesson); LDS stage converts layouts.

static __device__ __forceinline__ unsigned short f2bf(float f) {
    union { __hip_bfloat16 h; unsigned short u; } cv;
    cv.h = __float2bfloat16(f);
    return cv.u;
}
static __device__ __forceinline__ unsigned int f2bf2(float a, float b) {
    return (unsigned int)f2bf(a) | ((unsigned int)f2bf(b) << 16);
}
static __device__ __forceinline__ float blo(unsigned int w) { return __uint_as_float(w << 16); }
static __device__ __forceinline__ float bhi(unsigned int w) { return __uint_as_float(w & 0xffff0000u); }

// Per-wave phase fence: drain LDS ops, forbid compiler motion across (rule #18).
#define WSYNC() do { asm volatile("s_waitcnt lgkmcnt(0)" ::: "memory"); \
                     __builtin_amdgcn_sched_barrier(0); } while (0)

__global__ __launch_bounds__(768, 3)
void fused_block(const float* __restrict__ xg,
                 const float* __restrict__ Wq, const float* __restrict__ Wk,
                 const float* __restrict__ Wv, const float* __restrict__ Wp,
                 const float* __restrict__ bp, const float* __restrict__ W1,
                 const float* __restrict__ b1, const float* __restrict__ W2,
                 const float* __restrict__ b2, const float* __restrict__ g1,
                 const float* __restrict__ be1, const float* __restrict__ g2,
                 const float* __restrict__ be2, float* __restrict__ out,
                 int nPairsTotal)
{
    __shared__ __align__(16) unsigned char LDS[163840];

    const int tid  = threadIdx.x;
    const int lane = tid & 63;
    const int wid  = tid >> 6;        // 0..11
    const int fr   = lane & 15;       // MFMA fragment row/col index
    const int fg   = lane >> 4;       // MFMA fragment k-group
    const int xr   = lane >> 2;       // x row owned by this lane (0..15)
    const int xc   = (lane & 3) * 16; // x col base (floats)

    // ---------------- weight preload into LDS (bf16 fragments) ----------------
    {
        unsigned short* lw = (unsigned short*)LDS;
        #pragma unroll 1
        for (int e = tid; e < 45056; e += 768) {
            int j  = e & 7;
            int ln = (e >> 3) & 63;
            float src;
            if (e < 12288) {                       // QKV: col = 16*(sel*4+h)+d
                int ks = (e >> 9) & 1, nt = e >> 10;
                int k = 8*(ln>>4) + j + 32*ks;
                int d = ln & 15, h = nt & 3, sel = nt >> 2;
                const float* W = (sel == 0) ? Wq : ((sel == 1) ? Wk : Wv);
                src = W[h*1024 + k*16 + d];
            } else if (e < 28672) {                // W1 [64 x 256]
                int t = e - 12288;
                int ks = (t >> 9) & 1, nt = t >> 10;
                int k = 8*(ln>>4) + j + 32*ks;
                src = W1[k*256 + 16*nt + (ln & 15)];
            } else {                               // W2 [256 x 64]
                int t = e - 28672;
                int nt = (t >> 9) & 3, ksl = t >> 11;
                int k = 32*ksl + 8*(ln>>4) + j;
                src = W2[k*64 + 16*nt + (ln & 15)];
            }
            lw[e] = f2bf(src);
        }
    }

    // Wp fragments in registers
    bf16x8 wpf[4][2];
    #pragma unroll
    for (int nt = 0; nt < 4; ++nt)
        #pragma unroll
        for (int ks = 0; ks < 2; ++ks) {
            bf16x8 v;
            #pragma unroll
            for (int j = 0; j < 8; ++j)
                v[j] = (short)f2bf(Wp[(8*fg + j + 32*ks)*64 + 16*nt + fr]);
            wpf[nt][ks] = v;
        }

    // per-lane parameters
    float g1v[16], be1v[16], g2v[16], be2v[16];
    #pragma unroll
    for (int j = 0; j < 16; ++j) {
        int c = xc + j;
        g1v[j] = g1[c]; be1v[j] = be1[c]; g2v[j] = g2[c]; be2v[j] = be2[c];
    }
    float b1v[16], bpv[4], b2v[4];
    #pragma unroll
    for (int nt = 0; nt < 16; ++nt) b1v[nt] = b1[16*nt + fr];
    #pragma unroll
    for (int nt = 0; nt < 4; ++nt) { bpv[nt] = bp[16*nt + fr]; b2v[nt] = b2[16*nt + fr]; }

    __syncthreads();

    unsigned char* arena = LDS + 90112 + wid * 6144;
    unsigned short* qH  = (unsigned short*)(arena);          // + P overlay
    unsigned short* kH  = (unsigned short*)(arena + 2048);
    unsigned short* vT  = (unsigned short*)(arena + 4096);
    unsigned short* hB  = (unsigned short*)(arena);          // [16][72] bounce overlay
    unsigned short* sl0 = (unsigned short*)(arena);          // MLP slice dbuf overlay
    unsigned short* sl1 = (unsigned short*)(arena + 1280);
    unsigned char*  stg = arena + 2048;                      // 4 KB f32 x/out stage

    // stage offsets (bytes), XOR-swizzled to bank floor; same perm both sides
    int linOff[4], rowOff[4];
    #pragma unroll
    for (int i = 0; i < 4; ++i) {
        int bl = 16*lane + 1024*i;                 // linear (global-coalesced) side
        int br = 256*xr + 64*(lane & 3) + 16*i;    // row-ownership side
        linOff[i] = bl ^ (((bl >> 8) & 7) << 4);
        rowOff[i] = br ^ (((br >> 8) & 7) << 4);
    }

    // B-fragment read from weight LDS
    #define WB(F) (*(const bf16x8*)(LDS + ((F) << 10) + (lane << 4)))

    const int pipe = blockIdx.x * 12 + wid;   // 256 blocks * 12 waves = 3072 pipes

    const bf16x8 zero8 = {0,0,0,0,0,0,0,0};
    const short onebf = (short)0x3F80;
    const bf16x8 ones8 = {onebf,onebf,onebf,onebf,onebf,onebf,onebf,onebf};

    // prologue: coalesced load of first tile (lane l <-> floats 4l+256i)
    f32x4 cv[4];
    if (pipe < nPairsTotal) {
        const float* xb0 = xg + (size_t)pipe * 1024;
        #pragma unroll
        for (int i = 0; i < 4; ++i)
            cv[i] = *(const f32x4*)(xb0 + 4*lane + 256*i);
    }

    #pragma unroll 1
    for (int gp = pipe; gp < nPairsTotal; gp += 3072) {
        float* ob = out + (size_t)gp * 1024;

        // ---- stage current tile (linear) -> read back row-major ----
        #pragma unroll
        for (int i = 0; i < 4; ++i)
            *((f32x4*)(stg + linOff[i])) = cv[i];
        {   // issue next-tile coalesced prefetch (in flight across iteration)
            int gpn = gp + 3072;
            if (gpn < nPairsTotal) {
                const float* xbn = xg + (size_t)gpn * 1024;
                #pragma unroll
                for (int i = 0; i < 4; ++i)
                    cv[i] = *(const f32x4*)(xbn + 4*lane + 256*i);
            }
        }
        WSYNC();
        f32x4 xv[4];
        #pragma unroll
        for (int i = 0; i < 4; ++i)
            xv[i] = *((const f32x4*)(stg + rowOff[i]));

        // ---- LN1 -> h (bf16) -> hB ----
        {
            float s = 0.f, ss = 0.f;
            #pragma unroll
            for (int i = 0; i < 4; ++i)
                #pragma unroll
                for (int j = 0; j < 4; ++j) { float v = xv[i][j]; s += v; ss += v*v; }
            s += __shfl_xor(s, 1, 64); ss += __shfl_xor(ss, 1, 64);
            s += __shfl_xor(s, 2, 64); ss += __shfl_xor(ss, 2, 64);
            float mu  = s * 0.015625f;
            float inv = rsqrtf(ss * 0.015625f - mu*mu + 1e-5f);
            #pragma unroll
            for (int i = 0; i < 4; ++i) {
                float y0 = (xv[i][0]-mu)*inv*g1v[4*i+0] + be1v[4*i+0];
                float y1 = (xv[i][1]-mu)*inv*g1v[4*i+1] + be1v[4*i+1];
                float y2 = (xv[i][2]-mu)*inv*g1v[4*i+2] + be1v[4*i+2];
                float y3 = (xv[i][3]-mu)*inv*g1v[4*i+3] + be1v[4*i+3];
                *((uint2*)(hB + xr*72 + xc + 4*i)) = make_uint2(f2bf2(y0,y1), f2bf2(y2,y3));
            }
        }
        WSYNC();

        // ---- QKV = h @ [Wq|Wk|Wv] -> qH/kH/vT ----
        {
            bf16x8 a0 = *(const bf16x8*)(hB + fr*72 + 8*fg);
            bf16x8 a1 = *(const bf16x8*)(hB + fr*72 + 8*fg + 32);
            #pragma unroll
            for (int nt = 0; nt < 12; ++nt) {
                bf16x8 u0 = WB(nt*2+0);
                bf16x8 u1 = WB(nt*2+1);
                f32x4 acc = {0.f, 0.f, 0.f, 0.f};
                acc = __builtin_amdgcn_mfma_f32_16x16x32_bf16(a0, u0, acc, 0, 0, 0);
                acc = __builtin_amdgcn_mfma_f32_16x16x32_bf16(a1, u1, acc, 0, 0, 0);
                int hd = nt & 3;
                if (nt < 4) {
                    #pragma unroll
                    for (int r = 0; r < 4; ++r)
                        qH[hd*256 + (4*fg + r)*16 + fr] = f2bf(acc[r]);
                } else if (nt < 8) {
                    #pragma unroll
                    for (int r = 0; r < 4; ++r)
                        kH[hd*256 + (4*fg + r)*16 + fr] = f2bf(acc[r]);
                } else {   // transposed [d=fr][tk=4fg+r]; packed store
                    *((uint2*)(vT + hd*256 + fr*16 + 4*fg)) =
                        make_uint2(f2bf2(acc[0],acc[1]), f2bf2(acc[2],acc[3]));
                }
            }
        }
        WSYNC();

        // ---- attention scores + exp (no max-sub; |s|<=~2 by construction) ----
        #pragma unroll
        for (int hd = 0; hd < 4; ++hd) {
            bf16x8 qf = zero8, kf = zero8;
            if (fg < 2) {
                qf = *(const bf16x8*)(qH + hd*256 + fr*16 + 8*fg);
                kf = *(const bf16x8*)(kH + hd*256 + fr*16 + 8*fg);
            }
            f32x4 s = {0.f,0.f,0.f,0.f};
            s = __builtin_amdgcn_mfma_f32_16x16x32_bf16(qf, kf, s, 0, 0, 0);
            #pragma unroll
            for (int r = 0; r < 4; ++r) {   // D: S[row=4fg+r][tk=fr]
                int row = 4*fg + r;
                bool valid = (((row ^ fr) & 8) == 0) && ((fr & 7) <= (row & 7));
                float e = valid ? __expf(s[r] * 0.125f) : 0.f;   // scale = C^-0.5
                qH[hd*256 + row*16 + fr] = f2bf(e);              // P overlays qH
            }
        }
        WSYNC();

        // ---- PV + ones-MFMA row-sum; O -> hB (all reads precede stores) ----
        {
            f32x4 o[4], rs[4];
            #pragma unroll
            for (int pp = 0; pp < 2; ++pp) {
                bf16x8 pf0 = zero8, vf0 = zero8, pf1 = zero8, vf1 = zero8;
                if (fg < 2) {
                    pf0 = *(const bf16x8*)(qH + (2*pp+0)*256 + fr*16 + 8*fg);
                    vf0 = *(const bf16x8*)(vT + (2*pp+0)*256 + fr*16 + 8*fg);
                    pf1 = *(const bf16x8*)(qH + (2*pp+1)*256 + fr*16 + 8*fg);
                    vf1 = *(const bf16x8*)(vT + (2*pp+1)*256 + fr*16 + 8*fg);
                }
                f32x4 z = {0.f,0.f,0.f,0.f};
                o[2*pp+0]  = __builtin_amdgcn_mfma_f32_16x16x32_bf16(pf0, vf0,   z, 0,0,0);
                rs[2*pp+0] = __builtin_amdgcn_mfma_f32_16x16x32_bf16(pf0, ones8, z, 0,0,0);
                o[2*pp+1]  = __builtin_amdgcn_mfma_f32_16x16x32_bf16(pf1, vf1,   z, 0,0,0);
                rs[2*pp+1] = __builtin_amdgcn_mfma_f32_16x16x32_bf16(pf1, ones8, z, 0,0,0);
            }
            WSYNC();   // all P/vT reads drained before O stores below
            #pragma unroll
            for (int hd = 0; hd < 4; ++hd)
                #pragma unroll
                for (int r = 0; r < 4; ++r) {
                    float ov = o[hd][r] * __builtin_amdgcn_rcpf(rs[hd][r]);
                    hB[(4*fg + r)*72 + 16*hd + fr] = f2bf(ov);
                }
        }
        WSYNC();

        // ---- proj: sa = attn @ Wp + bp (reads hB, rewrites hB; MFMA-gated) ----
        {
            bf16x8 p0 = *(const bf16x8*)(hB + fr*72 + 8*fg);
            bf16x8 p1 = *(const bf16x8*)(hB + fr*72 + 8*fg + 32);
            f32x4 sacc[4];
            #pragma unroll
            for (int nt = 0; nt < 4; ++nt) {
                f32x4 acc = {0.f,0.f,0.f,0.f};
                acc = __builtin_amdgcn_mfma_f32_16x16x32_bf16(p0, wpf[nt][0], acc, 0,0,0);
                acc = __builtin_amdgcn_mfma_f32_16x16x32_bf16(p1, wpf[nt][1], acc, 0,0,0);
                sacc[nt] = acc;
            }
            #pragma unroll
            for (int nt = 0; nt < 4; ++nt)
                #pragma unroll
                for (int r = 0; r < 4; ++r)
                    hB[(4*fg + r)*72 + 16*nt + fr] = f2bf(sacc[nt][r] + bpv[nt]);
        }
        WSYNC();

        // ---- residual 1 (own cells), LN2 in-place -> hB ----
        #pragma unroll
        for (int i = 0; i < 4; ++i) {
            uint2 w = *((const uint2*)(hB + xr*72 + xc + 4*i));
            xv[i][0] += blo(w.x); xv[i][1] += bhi(w.x);
            xv[i][2] += blo(w.y); xv[i][3] += bhi(w.y);
        }
        {
            float s = 0.f, ss = 0.f;
            #pragma unroll
            for (int i = 0; i < 4; ++i)
                #pragma unroll
                for (int j = 0; j < 4; ++j) { float v = xv[i][j]; s += v; ss += v*v; }
            s += __shfl_xor(s, 1, 64); ss += __shfl_xor(ss, 1, 64);
            s += __shfl_xor(s, 2, 64); ss += __shfl_xor(ss, 2, 64);
            float mu  = s * 0.015625f;
            float inv = rsqrtf(ss * 0.015625f - mu*mu + 1e-5f);
            #pragma unroll
            for (int i = 0; i < 4; ++i) {
                float y0 = (xv[i][0]-mu)*inv*g2v[4*i+0] + be2v[4*i+0];
                float y1 = (xv[i][1]-mu)*inv*g2v[4*i+1] + be2v[4*i+1];
                float y2 = (xv[i][2]-mu)*inv*g2v[4*i+2] + be2v[4*i+2];
                float y3 = (xv[i][3]-mu)*inv*g2v[4*i+3] + be2v[4*i+3];
                *((uint2*)(hB + xr*72 + xc + 4*i)) = make_uint2(f2bf2(y0,y1), f2bf2(y2,y3));
            }
        }
        WSYNC();

        // ---- MLP, software-pipelined: W2(np-1) overlaps slice-store(np) ----
        bf16x8 c0 = *(const bf16x8*)(hB + fr*72 + 8*fg);
        bf16x8 c1 = *(const bf16x8*)(hB + fr*72 + 8*fg + 32);
        f32x4 ff[4];
        #pragma unroll
        for (int nt = 0; nt < 4; ++nt) { f32x4 z = {0.f,0.f,0.f,0.f}; ff[nt] = z; }

        #pragma unroll
        for (int q = 0; q < 2; ++q) {          // prologue: W1 tiles of np=0 -> sl0
            f32x4 acc = {0.f,0.f,0.f,0.f};
            acc = __builtin_amdgcn_mfma_f32_16x16x32_bf16(c0, WB(24 + q*2 + 0), acc, 0,0,0);
            acc = __builtin_amdgcn_mfma_f32_16x16x32_bf16(c1, WB(24 + q*2 + 1), acc, 0,0,0);
            #pragma unroll
            for (int r = 0; r < 4; ++r)
                sl0[(4*fg + r)*40 + 16*q + fr] = f2bf(fmaxf(acc[r] + b1v[q], 0.f));
        }
        WSYNC();
        bf16x8 asv = *(const bf16x8*)(sl0 + fr*40 + 8*fg);

        #pragma unroll
        for (int np = 1; np < 8; ++np) {
            unsigned short* sl = (np & 1) ? sl1 : sl0;
            #pragma unroll
            for (int q = 0; q < 2; ++q) {      // W1 tiles of np
                int nt1 = 2*np + q;
                f32x4 acc = {0.f,0.f,0.f,0.f};
                acc = __builtin_amdgcn_mfma_f32_16x16x32_bf16(c0, WB(24 + nt1*2 + 0), acc, 0,0,0);
                acc = __builtin_amdgcn_mfma_f32_16x16x32_bf16(c1, WB(24 + nt1*2 + 1), acc, 0,0,0);
                #pragma unroll
                for (int r = 0; r < 4; ++r)
                    sl[(4*fg + r)*40 + 16*q + fr] = f2bf(fmaxf(acc[r] + b1v[nt1], 0.f));
            }
            #pragma unroll
            for (int nt2 = 0; nt2 < 4; ++nt2)  // W2 of np-1 (overlaps store latency)
                ff[nt2] = __builtin_amdgcn_mfma_f32_16x16x32_bf16(
                              asv, WB(56 + (np-1)*4 + nt2), ff[nt2], 0,0,0);
            WSYNC();
            asv = *(const bf16x8*)(sl + fr*40 + 8*fg);
        }
        #pragma unroll
        for (int nt2 = 0; nt2 < 4; ++nt2)      // epilogue: W2 of np=7
            ff[nt2] = __builtin_amdgcn_mfma_f32_16x16x32_bf16(
                          asv, WB(56 + 28 + nt2), ff[nt2], 0,0,0);

        // ---- +b2 -> hB (gated by last slice read via MFMA) ----
        #pragma unroll
        for (int nt2 = 0; nt2 < 4; ++nt2)
            #pragma unroll
            for (int r = 0; r < 4; ++r)
                hB[(4*fg + r)*72 + 16*nt2 + fr] = f2bf(ff[nt2][r] + b2v[nt2]);
        WSYNC();

        // ---- residual 2: read ALL hB cells first, then stage row-major ----
        f32x4 ov[4];
        #pragma unroll
        for (int i = 0; i < 4; ++i) {
            uint2 w = *((const uint2*)(hB + xr*72 + xc + 4*i));
            f32x4 o = xv[i];
            o[0] += blo(w.x); o[1] += bhi(w.x);
            o[2] += blo(w.y); o[3] += bhi(w.y);
            ov[i] = o;
        }
        __builtin_amdgcn_sched_barrier(0);   // keep all hB reads before stage writes
        #pragma unroll
        for (int i = 0; i < 4; ++i)
            *((f32x4*)(stg + rowOff[i])) = ov[i];
        WSYNC();

        // ---- coalesced store (1 KB contiguous per instruction) ----
        #pragma unroll
        for (int i = 0; i < 4; ++i) {
            f32x4 t = *((const f32x4*)(stg + linOff[i]));
            *((f32x4*)(ob + 4*lane + 256*i)) = t;
        }
        WSYNC();   // stage reads drained before next iteration's stage writes
    }
    #undef WB
}

extern "C" void kernel_launch(void* const* d_in, const int* in_sizes, int n_in,
                              void* d_out, int out_size, void* d_ws, size_t ws_size,
                              hipStream_t stream) {
    const float* x   = (const float*)d_in[0];
    const float* Wq  = (const float*)d_in[1];
    const float* Wk  = (const float*)d_in[2];
    const float* Wv  = (const float*)d_in[3];
    const float* Wp  = (const float*)d_in[4];
    const float* bp  = (const float*)d_in[5];
    const float* W1  = (const float*)d_in[6];
    const float* b1  = (const float*)d_in[7];
    const float* W2  = (const float*)d_in[8];
    const float* b2  = (const float*)d_in[9];
    const float* g1  = (const float*)d_in[10];
    const float* be1 = (const float*)d_in[11];
    const float* g2  = (const float*)d_in[12];
    const float* be2 = (const float*)d_in[13];
    int nPairs = in_sizes[0] / 1024;   // (B*T*C) / (2*8*64) = 32768
    fused_block<<<dim3(256), dim3(768), 0, stream>>>(
        x, Wq, Wk, Wv, Wp, bp, W1, b1, W2, b2, g1, be1, g2, be2,
        (float*)d_out, nPairs);
}

// Round 8
// 146.241 us; speedup vs baseline: 1.4156x; 1.3815x over previous
//
#include <hip/hip_runtime.h>
#include <hip/hip_bf16.h>
#include <stdint.h>

typedef __attribute__((ext_vector_type(8))) short bf16x8;
typedef __attribute__((ext_vector_type(4))) float f32x4;

// LDS map (bytes):
//   [0, 98304)  weight B-fragments, bf16: frag f at byte f*1024 + lane*16
//     f 0..23: QKV (nt=sel*4+head, f=nt*2+ks)   f 24..55: W1 (f=24+nt*2+ks)
//     f 56..87: W2 (f=56+ksl*4+nt)              f 88..95: Wp (f=88+nt*2+ks)
//   [98304, 159744) 10 per-wave arenas of 6144 B, overlaid:
//     +0    qH [4][16][16] bf16  (P overlay; hB[16][72] bounce; sl0/sl1 in MLP)
//     +2048 kH [4][16][16]
//     +4096 vT [4][16 d][16 tk]
//   [159744, 160768) LN params f32: g1@0, be1@64, g2@128, be2@192 (floats)
// Register-pressure note (round-7 lesson): __launch_bounds__ min-waves caps
// VGPRs; params/Wp moved to LDS so demand ~150 < 170 cap -> no scratch spills.

static __device__ __forceinline__ unsigned short f2bf(float f) {
    union { __hip_bfloat16 h; unsigned short u; } cv;
    cv.h = __float2bfloat16(f);
    return cv.u;
}
static __device__ __forceinline__ unsigned int f2bf2(float a, float b) {
    return (unsigned int)f2bf(a) | ((unsigned int)f2bf(b) << 16);
}
static __device__ __forceinline__ float blo(unsigned int w) { return __uint_as_float(w << 16); }
static __device__ __forceinline__ float bhi(unsigned int w) { return __uint_as_float(w & 0xffff0000u); }

// Per-wave phase fence: drain LDS ops, forbid compiler motion across (rule #18).
#define WSYNC() do { asm volatile("s_waitcnt lgkmcnt(0)" ::: "memory"); \
                     __builtin_amdgcn_sched_barrier(0); } while (0)

__global__ __launch_bounds__(640, 3)
void fused_block(const float* __restrict__ xg,
                 const float* __restrict__ Wq, const float* __restrict__ Wk,
                 const float* __restrict__ Wv, const float* __restrict__ Wp,
                 const float* __restrict__ bp, const float* __restrict__ W1,
                 const float* __restrict__ b1, const float* __restrict__ W2,
                 const float* __restrict__ b2, const float* __restrict__ g1,
                 const float* __restrict__ be1, const float* __restrict__ g2,
                 const float* __restrict__ be2, float* __restrict__ out,
                 int nPairsTotal)
{
    __shared__ __align__(16) unsigned char LDS[160768];

    const int tid  = threadIdx.x;
    const int lane = tid & 63;
    const int wid  = tid >> 6;        // 0..9
    const int fr   = lane & 15;       // MFMA fragment row/col index
    const int fg   = lane >> 4;       // MFMA fragment k-group
    const int xr   = lane >> 2;       // x row owned by this lane (0..15)
    const int xc   = (lane & 3) * 16; // x col base (floats)

    // ---------------- weight preload into LDS (bf16 fragments) ----------------
    {
        unsigned short* lw = (unsigned short*)LDS;
        #pragma unroll 1
        for (int e = tid; e < 49152; e += 640) {
            int j  = e & 7;
            int ln = (e >> 3) & 63;
            float src;
            if (e < 12288) {                       // QKV: col = 16*(sel*4+h)+d
                int ks = (e >> 9) & 1, nt = e >> 10;
                int k = 8*(ln>>4) + j + 32*ks;
                int d = ln & 15, h = nt & 3, sel = nt >> 2;
                const float* W = (sel == 0) ? Wq : ((sel == 1) ? Wk : Wv);
                src = W[h*1024 + k*16 + d];
            } else if (e < 28672) {                // W1 [64 x 256]
                int t = e - 12288;
                int ks = (t >> 9) & 1, nt = t >> 10;
                int k = 8*(ln>>4) + j + 32*ks;
                src = W1[k*256 + 16*nt + (ln & 15)];
            } else if (e < 45056) {                // W2 [256 x 64]
                int t = e - 28672;
                int nt = (t >> 9) & 3, ksl = t >> 11;
                int k = 32*ksl + 8*(ln>>4) + j;
                src = W2[k*64 + 16*nt + (ln & 15)];
            } else {                               // Wp [64 x 64]
                int t = (e >> 9) - 88; int ks = t & 1, nt = t >> 1;
                int k = 8*(ln>>4) + j + 32*ks;
                src = Wp[k*64 + 16*nt + (ln & 15)];
            }
            lw[e] = f2bf(src);
        }
    }
    // LN params -> LDS (block-shared, f32)
    float* pgb = (float*)(LDS + 159744);
    if (tid < 256) {
        int a = tid >> 6, c = tid & 63;
        float v = (a == 0) ? g1[c] : (a == 1) ? be1[c] : (a == 2) ? g2[c] : be2[c];
        pgb[a*64 + c] = v;
    }

    // per-lane bias registers (small)
    float b1v[16], bpv[4], b2v[4];
    #pragma unroll
    for (int nt = 0; nt < 16; ++nt) b1v[nt] = b1[16*nt + fr];
    #pragma unroll
    for (int nt = 0; nt < 4; ++nt) { bpv[nt] = bp[16*nt + fr]; b2v[nt] = b2[16*nt + fr]; }

    __syncthreads();

    unsigned char* arena = LDS + 98304 + wid * 6144;
    unsigned short* qH  = (unsigned short*)(arena);          // + P overlay
    unsigned short* kH  = (unsigned short*)(arena + 2048);
    unsigned short* vT  = (unsigned short*)(arena + 4096);
    unsigned short* hB  = (unsigned short*)(arena);          // [16][72] bounce overlay
    unsigned short* sl0 = (unsigned short*)(arena);          // MLP slice dbuf overlay
    unsigned short* sl1 = (unsigned short*)(arena + 1280);

    // B-fragment read from weight LDS
    #define WB(F) (*(const bf16x8*)(LDS + ((F) << 10) + (lane << 4)))

    const int pipe = blockIdx.x * 10 + wid;   // 256 blocks * 10 waves = 2560 pipes

    const bf16x8 zero8 = {0,0,0,0,0,0,0,0};
    const short onebf = (short)0x3F80;
    const bf16x8 ones8 = {onebf,onebf,onebf,onebf,onebf,onebf,onebf,onebf};

    // prefetch first tile (lane owns row xr, cols xc..xc+15)
    f32x4 xn[4];
    if (pipe < nPairsTotal) {
        const float* xb0 = xg + (size_t)pipe * 1024;
        #pragma unroll
        for (int i = 0; i < 4; ++i)
            xn[i] = *(const f32x4*)(xb0 + xr*64 + xc + 4*i);
    }

    #pragma unroll 1
    for (int gp = pipe; gp < nPairsTotal; gp += 2560) {
        float* ob = out + (size_t)gp * 1024;

        f32x4 xv[4];
        #pragma unroll
        for (int i = 0; i < 4; ++i) xv[i] = xn[i];

        // issue next-tile prefetch (in flight across the whole iteration)
        {
            int gpn = gp + 2560;
            if (gpn < nPairsTotal) {
                const float* xbn = xg + (size_t)gpn * 1024;
                #pragma unroll
                for (int i = 0; i < 4; ++i)
                    xn[i] = *(const f32x4*)(xbn + xr*64 + xc + 4*i);
            }
        }

        // ---- LN1 -> h (bf16) -> hB ----
        {
            float s = 0.f, ss = 0.f;
            #pragma unroll
            for (int i = 0; i < 4; ++i)
                #pragma unroll
                for (int j = 0; j < 4; ++j) { float v = xv[i][j]; s += v; ss += v*v; }
            s += __shfl_xor(s, 1, 64); ss += __shfl_xor(ss, 1, 64);
            s += __shfl_xor(s, 2, 64); ss += __shfl_xor(ss, 2, 64);
            float mu  = s * 0.015625f;
            float inv = rsqrtf(ss * 0.015625f - mu*mu + 1e-5f);
            #pragma unroll
            for (int i = 0; i < 4; ++i) {
                f32x4 gv = *((const f32x4*)(pgb + xc + 4*i));
                f32x4 bv = *((const f32x4*)(pgb + 64 + xc + 4*i));
                float y0 = (xv[i][0]-mu)*inv*gv[0] + bv[0];
                float y1 = (xv[i][1]-mu)*inv*gv[1] + bv[1];
                float y2 = (xv[i][2]-mu)*inv*gv[2] + bv[2];
                float y3 = (xv[i][3]-mu)*inv*gv[3] + bv[3];
                *((uint2*)(hB + xr*72 + xc + 4*i)) = make_uint2(f2bf2(y0,y1), f2bf2(y2,y3));
            }
        }
        WSYNC();

        // ---- QKV = h @ [Wq|Wk|Wv] -> qH/kH/vT ----
        {
            bf16x8 a0 = *(const bf16x8*)(hB + fr*72 + 8*fg);
            bf16x8 a1 = *(const bf16x8*)(hB + fr*72 + 8*fg + 32);
            #pragma unroll
            for (int nt = 0; nt < 12; ++nt) {
                bf16x8 u0 = WB(nt*2+0);
                bf16x8 u1 = WB(nt*2+1);
                f32x4 acc = {0.f, 0.f, 0.f, 0.f};
                acc = __builtin_amdgcn_mfma_f32_16x16x32_bf16(a0, u0, acc, 0, 0, 0);
                acc = __builtin_amdgcn_mfma_f32_16x16x32_bf16(a1, u1, acc, 0, 0, 0);
                int hd = nt & 3;
                if (nt < 4) {
                    #pragma unroll
                    for (int r = 0; r < 4; ++r)
                        qH[hd*256 + (4*fg + r)*16 + fr] = f2bf(acc[r]);
                } else if (nt < 8) {
                    #pragma unroll
                    for (int r = 0; r < 4; ++r)
                        kH[hd*256 + (4*fg + r)*16 + fr] = f2bf(acc[r]);
                } else {   // transposed [d=fr][tk=4fg+r]; packed store
                    *((uint2*)(vT + hd*256 + fr*16 + 4*fg)) =
                        make_uint2(f2bf2(acc[0],acc[1]), f2bf2(acc[2],acc[3]));
                }
            }
        }
        WSYNC();

        // ---- attention scores + exp (no max-sub; |s|<=~2 by construction) ----
        #pragma unroll
        for (int hd = 0; hd < 4; ++hd) {
            bf16x8 qf = zero8, kf = zero8;
            if (fg < 2) {
                qf = *(const bf16x8*)(qH + hd*256 + fr*16 + 8*fg);
                kf = *(const bf16x8*)(kH + hd*256 + fr*16 + 8*fg);
            }
            f32x4 s = {0.f,0.f,0.f,0.f};
            s = __builtin_amdgcn_mfma_f32_16x16x32_bf16(qf, kf, s, 0, 0, 0);
            #pragma unroll
            for (int r = 0; r < 4; ++r) {   // D: S[row=4fg+r][tk=fr]
                int row = 4*fg + r;
                bool valid = (((row ^ fr) & 8) == 0) && ((fr & 7) <= (row & 7));
                float e = valid ? __expf(s[r] * 0.125f) : 0.f;   // scale = C^-0.5
                qH[hd*256 + row*16 + fr] = f2bf(e);              // P overlays qH
            }
        }
        WSYNC();

        // ---- PV + ones-MFMA row-sum; O -> hB (all reads precede stores) ----
        {
            f32x4 o[4], rs[4];
            #pragma unroll
            for (int pp = 0; pp < 2; ++pp) {
                bf16x8 pf0 = zero8, vf0 = zero8, pf1 = zero8, vf1 = zero8;
                if (fg < 2) {
                    pf0 = *(const bf16x8*)(qH + (2*pp+0)*256 + fr*16 + 8*fg);
                    vf0 = *(const bf16x8*)(vT + (2*pp+0)*256 + fr*16 + 8*fg);
                    pf1 = *(const bf16x8*)(qH + (2*pp+1)*256 + fr*16 + 8*fg);
                    vf1 = *(const bf16x8*)(vT + (2*pp+1)*256 + fr*16 + 8*fg);
                }
                f32x4 z = {0.f,0.f,0.f,0.f};
                o[2*pp+0]  = __builtin_amdgcn_mfma_f32_16x16x32_bf16(pf0, vf0,   z, 0,0,0);
                rs[2*pp+0] = __builtin_amdgcn_mfma_f32_16x16x32_bf16(pf0, ones8, z, 0,0,0);
                o[2*pp+1]  = __builtin_amdgcn_mfma_f32_16x16x32_bf16(pf1, vf1,   z, 0,0,0);
                rs[2*pp+1] = __builtin_amdgcn_mfma_f32_16x16x32_bf16(pf1, ones8, z, 0,0,0);
            }
            WSYNC();   // all P/vT reads drained before O stores below
            #pragma unroll
            for (int hd = 0; hd < 4; ++hd)
                #pragma unroll
                for (int r = 0; r < 4; ++r) {
                    float ov = o[hd][r] * __builtin_amdgcn_rcpf(rs[hd][r]);
                    hB[(4*fg + r)*72 + 16*hd + fr] = f2bf(ov);
                }
        }
        WSYNC();

        // ---- proj: sa = attn @ Wp + bp (Wp frags from LDS) ----
        {
            bf16x8 p0 = *(const bf16x8*)(hB + fr*72 + 8*fg);
            bf16x8 p1 = *(const bf16x8*)(hB + fr*72 + 8*fg + 32);
            f32x4 sacc[4];
            #pragma unroll
            for (int nt = 0; nt < 4; ++nt) {
                f32x4 acc = {0.f,0.f,0.f,0.f};
                acc = __builtin_amdgcn_mfma_f32_16x16x32_bf16(p0, WB(88 + nt*2 + 0), acc, 0,0,0);
                acc = __builtin_amdgcn_mfma_f32_16x16x32_bf16(p1, WB(88 + nt*2 + 1), acc, 0,0,0);
                sacc[nt] = acc;
            }
            #pragma unroll
            for (int nt = 0; nt < 4; ++nt)
                #pragma unroll
                for (int r = 0; r < 4; ++r)
                    hB[(4*fg + r)*72 + 16*nt + fr] = f2bf(sacc[nt][r] + bpv[nt]);
        }
        WSYNC();

        // ---- residual 1 (own cells), LN2 in-place -> hB ----
        #pragma unroll
        for (int i = 0; i < 4; ++i) {
            uint2 w = *((const uint2*)(hB + xr*72 + xc + 4*i));
            xv[i][0] += blo(w.x); xv[i][1] += bhi(w.x);
            xv[i][2] += blo(w.y); xv[i][3] += bhi(w.y);
        }
        {
            float s = 0.f, ss = 0.f;
            #pragma unroll
            for (int i = 0; i < 4; ++i)
                #pragma unroll
                for (int j = 0; j < 4; ++j) { float v = xv[i][j]; s += v; ss += v*v; }
            s += __shfl_xor(s, 1, 64); ss += __shfl_xor(ss, 1, 64);
            s += __shfl_xor(s, 2, 64); ss += __shfl_xor(ss, 2, 64);
            float mu  = s * 0.015625f;
            float inv = rsqrtf(ss * 0.015625f - mu*mu + 1e-5f);
            #pragma unroll
            for (int i = 0; i < 4; ++i) {
                f32x4 gv = *((const f32x4*)(pgb + 128 + xc + 4*i));
                f32x4 bv = *((const f32x4*)(pgb + 192 + xc + 4*i));
                float y0 = (xv[i][0]-mu)*inv*gv[0] + bv[0];
                float y1 = (xv[i][1]-mu)*inv*gv[1] + bv[1];
                float y2 = (xv[i][2]-mu)*inv*gv[2] + bv[2];
                float y3 = (xv[i][3]-mu)*inv*gv[3] + bv[3];
                *((uint2*)(hB + xr*72 + xc + 4*i)) = make_uint2(f2bf2(y0,y1), f2bf2(y2,y3));
            }
        }
        WSYNC();

        // ---- MLP, software-pipelined: W2(np-1) overlaps slice-store(np) ----
        bf16x8 c0 = *(const bf16x8*)(hB + fr*72 + 8*fg);
        bf16x8 c1 = *(const bf16x8*)(hB + fr*72 + 8*fg + 32);
        f32x4 ff[4];
        #pragma unroll
        for (int nt = 0; nt < 4; ++nt) { f32x4 z = {0.f,0.f,0.f,0.f}; ff[nt] = z; }

        #pragma unroll
        for (int q = 0; q < 2; ++q) {          // prologue: W1 tiles of np=0 -> sl0
            f32x4 acc = {0.f,0.f,0.f,0.f};
            acc = __builtin_amdgcn_mfma_f32_16x16x32_bf16(c0, WB(24 + q*2 + 0), acc, 0,0,0);
            acc = __builtin_amdgcn_mfma_f32_16x16x32_bf16(c1, WB(24 + q*2 + 1), acc, 0,0,0);
            #pragma unroll
            for (int r = 0; r < 4; ++r)
                sl0[(4*fg + r)*40 + 16*q + fr] = f2bf(fmaxf(acc[r] + b1v[q], 0.f));
        }
        WSYNC();
        bf16x8 asv = *(const bf16x8*)(sl0 + fr*40 + 8*fg);

        #pragma unroll
        for (int np = 1; np < 8; ++np) {
            unsigned short* sl = (np & 1) ? sl1 : sl0;
            #pragma unroll
            for (int q = 0; q < 2; ++q) {      // W1 tiles of np
                int nt1 = 2*np + q;
                f32x4 acc = {0.f,0.f,0.f,0.f};
                acc = __builtin_amdgcn_mfma_f32_16x16x32_bf16(c0, WB(24 + nt1*2 + 0), acc, 0,0,0);
                acc = __builtin_amdgcn_mfma_f32_16x16x32_bf16(c1, WB(24 + nt1*2 + 1), acc, 0,0,0);
                #pragma unroll
                for (int r = 0; r < 4; ++r)
                    sl[(4*fg + r)*40 + 16*q + fr] = f2bf(fmaxf(acc[r] + b1v[nt1], 0.f));
            }
            #pragma unroll
            for (int nt2 = 0; nt2 < 4; ++nt2)  // W2 of np-1 (overlaps store latency)
                ff[nt2] = __builtin_amdgcn_mfma_f32_16x16x32_bf16(
                              asv, WB(56 + (np-1)*4 + nt2), ff[nt2], 0,0,0);
            WSYNC();
            asv = *(const bf16x8*)(sl + fr*40 + 8*fg);
        }
        #pragma unroll
        for (int nt2 = 0; nt2 < 4; ++nt2)      // epilogue: W2 of np=7
            ff[nt2] = __builtin_amdgcn_mfma_f32_16x16x32_bf16(
                          asv, WB(56 + 28 + nt2), ff[nt2], 0,0,0);

        // ---- +b2 -> hB (gated by last slice read via MFMA) ----
        #pragma unroll
        for (int nt2 = 0; nt2 < 4; ++nt2)
            #pragma unroll
            for (int r = 0; r < 4; ++r)
                hB[(4*fg + r)*72 + 16*nt2 + fr] = f2bf(ff[nt2][r] + b2v[nt2]);
        WSYNC();

        // ---- residual 2 + store ----
        #pragma unroll
        for (int i = 0; i < 4; ++i) {
            uint2 w = *((const uint2*)(hB + xr*72 + xc + 4*i));
            f32x4 o = xv[i];
            o[0] += blo(w.x); o[1] += bhi(w.x);
            o[2] += blo(w.y); o[3] += bhi(w.y);
            *((f32x4*)(ob + xr*64 + xc + 4*i)) = o;
        }
        WSYNC();   // hB reads drained before next iteration's LN1 writes
    }
    #undef WB
}

extern "C" void kernel_launch(void* const* d_in, const int* in_sizes, int n_in,
                              void* d_out, int out_size, void* d_ws, size_t ws_size,
                              hipStream_t stream) {
    const float* x   = (const float*)d_in[0];
    const float* Wq  = (const float*)d_in[1];
    const float* Wk  = (const float*)d_in[2];
    const float* Wv  = (const float*)d_in[3];
    const float* Wp  = (const float*)d_in[4];
    const float* bp  = (const float*)d_in[5];
    const float* W1  = (const float*)d_in[6];
    const float* b1  = (const float*)d_in[7];
    const float* W2  = (const float*)d_in[8];
    const float* b2  = (const float*)d_in[9];
    const float* g1  = (const float*)d_in[10];
    const float* be1 = (const float*)d_in[11];
    const float* g2  = (const float*)d_in[12];
    const float* be2 = (const float*)d_in[13];
    int nPairs = in_sizes[0] / 1024;   // (B*T*C) / (2*8*64) = 32768
    fused_block<<<dim3(256), dim3(640), 0, stream>>>(
        x, Wq, Wk, Wv, Wp, bp, W1, b1, W2, b2, g1, be1, g2, be2,
        (float*)d_out, nPairs);
}